// Round 1
// baseline (1971.599 us; speedup 1.0000x reference)
//
#include <hip/hip_runtime.h>
#include <math.h>

#define B_ 512
#define N_ 101
#define H_ 128
#define T_ 140

// =====================================================================
// Generic tiled GEMM: C tile [128 rows x 32 cols] = A(rows x 128) @ B(128x128)
// grid.x = nRowBlk*4 (rb = x>>2, cb = x&3), grid.y = nMat
// =====================================================================
__global__ __launch_bounds__(256) void gemm_tile(
    const float* __restrict__ Abase, long long aStride,
    const float* __restrict__ Bbase, long long bStride,
    float* __restrict__ Cbase, long long cStride,
    int transB)
{
  int mat = blockIdx.y;
  int rb  = blockIdx.x >> 2;
  int cb  = blockIdx.x & 3;
  const float* A = Abase + (long long)mat * aStride + (long long)rb * 128 * 128;
  const float* B = Bbase + (long long)mat * bStride;
  float*       C = Cbase + (long long)mat * cStride + (long long)rb * 128 * 128;
  int tid = threadIdx.x;
  int cc  = cb * 32 + (tid & 7) * 4;
  int r0  = tid >> 3;  // 0..31
  float4 acc0 = {0,0,0,0}, acc1 = {0,0,0,0}, acc2 = {0,0,0,0}, acc3 = {0,0,0,0};
  for (int k = 0; k < 128; ++k) {
    float4 b4;
    if (!transB) {
      b4 = *(const float4*)(B + k * 128 + cc);
    } else {
      b4.x = B[(cc + 0) * 128 + k];
      b4.y = B[(cc + 1) * 128 + k];
      b4.z = B[(cc + 2) * 128 + k];
      b4.w = B[(cc + 3) * 128 + k];
    }
    float a0 = A[(r0 +  0) * 128 + k];
    float a1 = A[(r0 + 32) * 128 + k];
    float a2 = A[(r0 + 64) * 128 + k];
    float a3 = A[(r0 + 96) * 128 + k];
    acc0.x += a0 * b4.x; acc0.y += a0 * b4.y; acc0.z += a0 * b4.z; acc0.w += a0 * b4.w;
    acc1.x += a1 * b4.x; acc1.y += a1 * b4.y; acc1.z += a1 * b4.z; acc1.w += a1 * b4.w;
    acc2.x += a2 * b4.x; acc2.y += a2 * b4.y; acc2.z += a2 * b4.z; acc2.w += a2 * b4.w;
    acc3.x += a3 * b4.x; acc3.y += a3 * b4.y; acc3.z += a3 * b4.z; acc3.w += a3 * b4.w;
  }
  *(float4*)(C + (r0 +  0) * 128 + cc) = acc0;
  *(float4*)(C + (r0 + 32) * 128 + cc) = acc1;
  *(float4*)(C + (r0 + 64) * 128 + cc) = acc2;
  *(float4*)(C + (r0 + 96) * 128 + cc) = acc3;
}

// wcap[j] = W_fc[128,:] @ W_w[:,j]
__global__ void wcap_kernel(const float* __restrict__ Wfc, const float* __restrict__ Ww,
                            float* __restrict__ wcap)
{
  int j = threadIdx.x;
  float s = 0.f;
  for (int k = 0; k < 128; ++k) s += Wfc[128 * 128 + k] * Ww[k * 128 + j];
  wcap[j] = s;
}

// =====================================================================
// Decode: one block per batch row, full 140-step scan in-block.
// =====================================================================
__global__ __launch_bounds__(256, 2) void decode_kernel(
    const float* __restrict__ enc,      // B,N,H
    const float* __restrict__ Wk,       // H,H
    const float* __restrict__ Wv,       // H,H
    const float* __restrict__ Wc,       // ws: W_pk @ W_attnfc^T
    const float* __restrict__ encW,     // ws: B,N,H  (enc @ W_fc[0:128] @ W_w)
    const float* __restrict__ Qpool,    // ws: T,B,H  (pool @ W_fc1^{t+1} @ W_w)
    const float* __restrict__ wcap,     // ws: H
    const float* __restrict__ capcity,  // B,1
    const float* __restrict__ demand,   // B,N
    float* __restrict__ out)            // [B*T actions as float][B logp]
{
  __shared__ __align__(16) float s_enc[N_ * 132];   // enc staging (init only), pad 132
  __shared__ __align__(16) float s_sc[8 * 104];     // scores u / sc
  __shared__ __align__(16) float s_Q[128];
  __shared__ __align__(16) float s_glim[128];
  __shared__ __align__(16) float s_part[256];
  __shared__ float s_dem[104];
  __shared__ float s_redV[4];
  __shared__ int   s_redI[4];
  __shared__ float s_redS[4];
  __shared__ unsigned long long s_ball[2];
  __shared__ unsigned long long s_mask[2];
  __shared__ unsigned long long s_m1[2];
  __shared__ int   s_idx;
  __shared__ float s_cap;
  __shared__ float s_cap0;

  const int b    = blockIdx.x;
  const int tid  = threadIdx.x;
  const int lane = tid & 63;
  const int wave = tid >> 6;
  const int an = tid & 127, aj = tid >> 7;   // role A: K/Kp2 row an, half aj
  const int bj = tid & 127, bh = tid >> 7;   // role B: V column bj, n-half bh

  // ---- stage enc[b] into LDS (row pad 132 floats) ----
  for (int idx = tid; idx < N_ * 32; idx += 256) {
    int row = idx >> 5, q = idx & 31;
    float4 v = *(const float4*)(enc + ((long long)b * N_ + row) * H_ + q * 4);
    float* d = s_enc + row * 132 + q * 4;
    d[0] = v.x; d[1] = v.y; d[2] = v.z; d[3] = v.w;
  }
  __syncthreads();

  // ---- V column slices into registers: vreg[nl] = V[bh*51+nl][bj] ----
  float vreg[51];
#pragma unroll
  for (int q = 0; q < 51; ++q) vreg[q] = 0.f;
  {
    const int base = bh * 51;
    for (int i4 = 0; i4 < 32; ++i4) {
      float w0 = Wv[(i4 * 4 + 0) * H_ + bj];
      float w1 = Wv[(i4 * 4 + 1) * H_ + bj];
      float w2 = Wv[(i4 * 4 + 2) * H_ + bj];
      float w3 = Wv[(i4 * 4 + 3) * H_ + bj];
#pragma unroll
      for (int nl = 0; nl < 51; ++nl) {
        if (base + nl < N_) {
          float4 e = *(const float4*)(s_enc + (base + nl) * 132 + i4 * 4);
          vreg[nl] += e.x * w0 + e.y * w1 + e.z * w2 + e.w * w3;
        }
      }
    }
  }

  // ---- K and Kp2 row slices into registers (role A) ----
  float kreg[64], preg[64];
#pragma unroll
  for (int q = 0; q < 64; ++q) { kreg[q] = 0.f; preg[q] = 0.f; }
  if (an < N_) {
    for (int i = 0; i < 128; ++i) {
      float e = s_enc[an * 132 + i];
      const float4* wk = (const float4*)(Wk + i * H_ + aj * 64);
      const float4* wc = (const float4*)(Wc + i * H_ + aj * 64);
#pragma unroll
      for (int q = 0; q < 16; ++q) {
        float4 a = wk[q];
        kreg[q * 4 + 0] += e * a.x; kreg[q * 4 + 1] += e * a.y;
        kreg[q * 4 + 2] += e * a.z; kreg[q * 4 + 3] += e * a.w;
        float4 c = wc[q];
        preg[q * 4 + 0] += e * c.x; preg[q * 4 + 1] += e * c.y;
        preg[q * 4 + 2] += e * c.z; preg[q * 4 + 3] += e * c.w;
      }
    }
  }

  // ---- demand + state init ----
  for (int n = tid; n < 104; n += 256) s_dem[n] = (n < N_) ? demand[(long long)b * N_ + n] : 0.f;
  if (tid == 0) {
    s_idx = 0;
    s_cap = capcity[b];
    s_cap0 = capcity[0];
    s_m1[0] = 1ull; s_m1[1] = 0ull;
  }
  __syncthreads();

  // initial mask = onehot(0) | demand > capcity[b]
  if (tid < 128) {
    int n = tid;
    bool pred;
    if (n <= 100) {
      bool m1b = (n < 64) ? ((s_m1[0] >> n) & 1ull) : ((s_m1[1] >> (n - 64)) & 1ull);
      pred = m1b || (s_dem[n] > s_cap);
    } else pred = true;
    unsigned long long bal = __ballot(pred);
    if (lane == 0) s_ball[wave] = bal;
  }
  __syncthreads();
  if (tid == 0) {
    unsigned long long lo = s_ball[0];
    unsigned long long hi = s_ball[1] & ((1ull << 37) - 1ull);
    if (lo == ~0ull && hi == ((1ull << 37) - 1ull)) lo &= ~1ull;
    s_mask[0] = lo; s_mask[1] = hi;
  }
  __syncthreads();

  float logpAcc = 0.f;
  bool  doneCur = false;
  const float invSqrtH = 0.08838834764831845f;  // 1/sqrt(128)

  for (int t = 0; t < T_; ++t) {
    // ---- ph1: Q = encW[b,idx] + cap*wcap + Qpool[t,b] ----
    if (tid < 128) {
      int idx = s_idx;
      float q = encW[((long long)b * N_ + idx) * H_ + tid]
              + s_cap * wcap[tid]
              + Qpool[((long long)t * B_ + b) * H_ + tid];
      s_Q[tid] = q;
    }
    __syncthreads();

    // ---- ph2: compat[h][an] (role A), masked, *0.25 ----
    if (an < N_) {
      const float4* q4 = (const float4*)(s_Q + aj * 64);
      bool mb = (an < 64) ? ((s_mask[0] >> an) & 1ull) : ((s_mask[1] >> (an - 64)) & 1ull);
#pragma unroll
      for (int h = 0; h < 4; ++h) {
        float c = 0.f;
#pragma unroll
        for (int q = 0; q < 4; ++q) {
          float4 qq = q4[h * 4 + q];
          c += qq.x * kreg[h * 16 + q * 4 + 0] + qq.y * kreg[h * 16 + q * 4 + 1]
             + qq.z * kreg[h * 16 + q * 4 + 2] + qq.w * kreg[h * 16 + q * 4 + 3];
        }
        s_sc[(aj * 4 + h) * 104 + an] = mb ? -INFINITY : 0.25f * c;
      }
    }
    __syncthreads();

    // ---- ph3: masked softmax per head (wave w: heads w, w+4) ----
#pragma unroll
    for (int rep = 0; rep < 2; ++rep) {
      int h = wave + rep * 4;
      float* srow = s_sc + h * 104;
      float v0 = srow[lane];
      float v1 = (lane < 37) ? srow[64 + lane] : -INFINITY;
      float m = fmaxf(v0, v1);
#pragma unroll
      for (int off = 32; off > 0; off >>= 1) m = fmaxf(m, __shfl_xor(m, off));
      float e0 = expf(v0 - m);
      float e1 = (lane < 37) ? expf(v1 - m) : 0.f;
      float s = e0 + e1;
#pragma unroll
      for (int off = 32; off > 0; off >>= 1) s += __shfl_xor(s, off);
      srow[lane] = e0 / s;
      if (lane < 37) srow[64 + lane] = e1 / s;
    }
    __syncthreads();

    // ---- ph4: glimpse partial (role B) ----
    {
      int h = bj >> 4;
      const float* srow = s_sc + h * 104;
      float acc = 0.f;
      if (bh == 0) {
#pragma unroll
        for (int q = 0; q < 12; ++q) {
          float4 sv = *(const float4*)(srow + q * 4);
          acc += sv.x * vreg[q * 4 + 0] + sv.y * vreg[q * 4 + 1]
               + sv.z * vreg[q * 4 + 2] + sv.w * vreg[q * 4 + 3];
        }
        acc += srow[48] * vreg[48] + srow[49] * vreg[49] + srow[50] * vreg[50];
      } else {
        acc += srow[51] * vreg[0];
#pragma unroll
        for (int q = 0; q < 12; ++q) {
          float4 sv = *(const float4*)(srow + 52 + q * 4);
          acc += sv.x * vreg[1 + q * 4] + sv.y * vreg[2 + q * 4]
               + sv.z * vreg[3 + q * 4] + sv.w * vreg[4 + q * 4];
        }
        acc += srow[100] * vreg[49];
      }
      s_part[bh * 128 + bj] = acc;
    }
    __syncthreads();

    if (tid < 128) s_glim[tid] = s_part[tid] + s_part[128 + tid];
    __syncthreads();

    // ---- ph5: comp2 partial (role A) ----
    if (an < N_) {
      const float4* g4 = (const float4*)(s_glim + aj * 64);
      float c = 0.f;
#pragma unroll
      for (int q = 0; q < 16; ++q) {
        float4 g = g4[q];
        c += g.x * preg[q * 4 + 0] + g.y * preg[q * 4 + 1]
           + g.z * preg[q * 4 + 2] + g.w * preg[q * 4 + 3];
      }
      s_part[aj * 128 + an] = c;
    }
    __syncthreads();

    // ---- ph6: logits, wave max/argmax ----
    float logit = -INFINITY;
    if (tid < 128) {
      int n = tid;
      if (n < N_) {
        bool mb = (n < 64) ? ((s_mask[0] >> n) & 1ull) : ((s_mask[1] >> (n - 64)) & 1ull);
        if (!mb) {
          float tot = (s_part[n] + s_part[128 + n]) * invSqrtH;
          logit = 10.f * tanhf(tot);
        }
      }
      float v = logit; int ix = (n < N_) ? n : 127;
#pragma unroll
      for (int off = 32; off > 0; off >>= 1) {
        float v2 = __shfl_xor(v, off);
        int  i2 = __shfl_xor(ix, off);
        if (v2 > v || (v2 == v && i2 < ix)) { v = v2; ix = i2; }
      }
      if (lane == 0) { s_redV[wave] = v; s_redI[wave] = ix; }
    }
    __syncthreads();

    // ---- ph6b: combine, exp-sum, new-state + ballot (all tid<128 redundantly) ----
    int amaxL = 0; float capNewL = 0.f;
    unsigned long long m1loL = 0ull, m1hiL = 0ull;
    if (tid < 128) {
      float v0 = s_redV[0], v1 = s_redV[1];
      int  i0 = s_redI[0], i1 = s_redI[1];
      float vmax; int amax;
      if (v1 > v0 || (v1 == v0 && i1 < i0)) { vmax = v1; amax = i1; }
      else                                  { vmax = v0; amax = i0; }
      amaxL = amax;
      float e = expf(logit - vmax);
#pragma unroll
      for (int off = 32; off > 0; off >>= 1) e += __shfl_xor(e, off);
      if (lane == 0) s_redS[wave] = e;
      // state update (reference update_state + update_mask)
      capNewL = (amax == 0) ? s_cap0 : (s_cap - s_dem[amax]);
      m1loL = s_m1[0]; m1hiL = s_m1[1];
      if (amax < 64) m1loL |= (1ull << amax); else m1hiL |= (1ull << (amax - 64));
      m1loL = (m1loL & ~1ull) | (unsigned long long)(amax == 0);
      int n = tid; bool pred;
      if (n <= 100) {
        bool mb = (n < 64) ? ((m1loL >> n) & 1ull) : ((m1hiL >> (n - 64)) & 1ull);
        pred = mb || (s_dem[n] > capNewL);
      } else pred = true;
      unsigned long long bal = __ballot(pred);
      if (lane == 0) s_ball[wave] = bal;
    }
    __syncthreads();

    // ---- ph7: scalar finalize (thread 0) ----
    if (tid == 0) {
      float ss = s_redS[0] + s_redS[1];
      float lse = logf(ss);
      if (!doneCur) logpAcc -= lse;
      out[(long long)b * T_ + t] = (float)amaxL;
      unsigned long long lo = s_ball[0];
      unsigned long long hi = s_ball[1] & ((1ull << 37) - 1ull);
      if (lo == ~0ull && hi == ((1ull << 37) - 1ull)) lo &= ~1ull;
      s_mask[0] = lo; s_mask[1] = hi;
      s_m1[0] = m1loL; s_m1[1] = m1hiL;
      doneCur = ((int)__popcll(m1loL & ~1ull) + (int)__popcll(m1hiL)) >= (N_ - 1);
      s_idx = amaxL; s_cap = capNewL;
    }
    __syncthreads();
  }

  if (tid == 0) out[(long long)B_ * T_ + b] = logpAcc;
}

// =====================================================================
extern "C" void kernel_launch(void* const* d_in, const int* in_sizes, int n_in,
                              void* d_out, int out_size, void* d_ws, size_t ws_size,
                              hipStream_t stream)
{
  const float* enc   = (const float*)d_in[0];
  const float* pool  = (const float*)d_in[1];
  const float* cap   = (const float*)d_in[3];
  const float* dem   = (const float*)d_in[4];
  const float* W_fc  = (const float*)d_in[7];   // 129x128
  const float* W_fc1 = (const float*)d_in[8];   // 128x128
  const float* W_w   = (const float*)d_in[9];
  const float* W_kk  = (const float*)d_in[10];
  const float* W_vv  = (const float*)d_in[11];
  const float* W_at  = (const float*)d_in[12];
  const float* W_pk  = (const float*)d_in[13];
  float* out = (float*)d_out;
  float* ws  = (float*)d_ws;

  // workspace layout (floats), total ~81.7 MB
  float* Mbuf  = ws;                               // 141 * 16384 (M[s] = W_fc1^s, slot 0 unused)
  float* Abuf  = Mbuf + 141 * 16384;               // 140 * 16384 (A_t = M[t+1] @ W_w)
  float* Qpl   = Abuf + 140 * 16384;               // 140 * 512 * 128
  float* encW  = Qpl + 140 * 512 * 128;            // 512 * 101 * 128
  float* Wfw   = encW + 512 * 101 * 128;           // 16384
  float* Wc    = Wfw + 16384;                      // 16384
  float* wcapb = Wc + 16384;                       // 128

  // M[1] = W_fc1
  hipMemcpyAsync(Mbuf + 16384, W_fc1, 128 * 128 * sizeof(float),
                 hipMemcpyDeviceToDevice, stream);
  // Wfw = W_fc[0:128] @ W_w
  gemm_tile<<<dim3(4, 1), 256, 0, stream>>>(W_fc, 0, W_w, 0, Wfw, 0, 0);
  // Wc = W_pk @ W_attnfc^T
  gemm_tile<<<dim3(4, 1), 256, 0, stream>>>(W_pk, 0, W_at, 0, Wc, 0, 1);
  // wcap = W_fc[128,:] @ W_w
  wcap_kernel<<<1, 128, 0, stream>>>(W_fc, W_w, wcapb);
  // matrix powers by doubling: M[L+s] = M[s] @ M[L]
  for (int L = 1; L < 140; L <<= 1) {
    int cnt = (L < 140 - L) ? L : (140 - L);
    gemm_tile<<<dim3(4, cnt), 256, 0, stream>>>(
        Mbuf + 16384, 16384,
        Mbuf + (long long)L * 16384, 0,
        Mbuf + (long long)(L + 1) * 16384, 16384, 0);
  }
  // A_t = M[t+1] @ W_w
  gemm_tile<<<dim3(4, 140), 256, 0, stream>>>(Mbuf + 16384, 16384, W_w, 0, Abuf, 16384, 0);
  // Qpool[t] = pool @ A_t
  gemm_tile<<<dim3(16, 140), 256, 0, stream>>>(pool, 0, Abuf, 16384, Qpl, 65536, 0);
  // encW = enc @ Wfw  (51712 rows = 404 * 128)
  gemm_tile<<<dim3(404 * 4, 1), 256, 0, stream>>>(enc, 0, Wfw, 0, encW, 0, 0);
  // fused 140-step decode
  decode_kernel<<<512, 256, 0, stream>>>(enc, W_kk, W_vv, Wc, encW, Qpl, wcapb, cap, dem, out);
}

// Round 2
// 1736.087 us; speedup vs baseline: 1.1357x; 1.1357x over previous
//
#include <hip/hip_runtime.h>
#include <math.h>

#define B_ 512
#define N_ 101
#define H_ 128
#define T_ 140
#define M37 0x1FFFFFFFFFull

// lgkm-only barrier: does NOT drain vmcnt, so global prefetches/stores stay in flight
#define BAR() asm volatile("s_waitcnt lgkmcnt(0)\n\ts_barrier" ::: "memory")

// ---------------- DPP wave64 reductions (value-exact max; sum used only for lse) ----
template <int CTRL, int RM>
__device__ __forceinline__ float dpp_max_step(float x) {
  int t = __builtin_amdgcn_update_dpp((int)0xFF800000, __float_as_int(x), CTRL, RM, 0xF, false);
  return fmaxf(x, __int_as_float(t));
}
template <int CTRL, int RM>
__device__ __forceinline__ float dpp_add_step(float x) {
  int t = __builtin_amdgcn_update_dpp(0, __float_as_int(x), CTRL, RM, 0xF, false);
  return x + __int_as_float(t);
}
__device__ __forceinline__ float wave_max64(float x) {
  x = dpp_max_step<0x111, 0xF>(x);   // row_shr:1
  x = dpp_max_step<0x112, 0xF>(x);   // row_shr:2
  x = dpp_max_step<0x114, 0xF>(x);   // row_shr:4
  x = dpp_max_step<0x118, 0xF>(x);   // row_shr:8
  x = dpp_max_step<0x142, 0xA>(x);   // row_bcast15 -> rows 1,3
  x = dpp_max_step<0x143, 0xC>(x);   // row_bcast31 -> rows 2,3
  return __int_as_float(__builtin_amdgcn_readlane(__float_as_int(x), 63));
}
__device__ __forceinline__ float wave_sum64(float x) {
  x = dpp_add_step<0x111, 0xF>(x);
  x = dpp_add_step<0x112, 0xF>(x);
  x = dpp_add_step<0x114, 0xF>(x);
  x = dpp_add_step<0x118, 0xF>(x);
  x = dpp_add_step<0x142, 0xA>(x);
  x = dpp_add_step<0x143, 0xC>(x);
  return __int_as_float(__builtin_amdgcn_readlane(__float_as_int(x), 63));
}

// =====================================================================
// Generic tiled GEMM (unchanged from R1 — bit-exact producer of K/P/encW/Qpool)
// =====================================================================
__global__ __launch_bounds__(256) void gemm_tile(
    const float* __restrict__ Abase, long long aStride,
    const float* __restrict__ Bbase, long long bStride,
    float* __restrict__ Cbase, long long cStride,
    int transB)
{
  int mat = blockIdx.y;
  int rb  = blockIdx.x >> 2;
  int cb  = blockIdx.x & 3;
  const float* A = Abase + (long long)mat * aStride + (long long)rb * 128 * 128;
  const float* B = Bbase + (long long)mat * bStride;
  float*       C = Cbase + (long long)mat * cStride + (long long)rb * 128 * 128;
  int tid = threadIdx.x;
  int cc  = cb * 32 + (tid & 7) * 4;
  int r0  = tid >> 3;
  float4 acc0 = {0,0,0,0}, acc1 = {0,0,0,0}, acc2 = {0,0,0,0}, acc3 = {0,0,0,0};
  for (int k = 0; k < 128; ++k) {
    float4 b4;
    if (!transB) {
      b4 = *(const float4*)(B + k * 128 + cc);
    } else {
      b4.x = B[(cc + 0) * 128 + k];
      b4.y = B[(cc + 1) * 128 + k];
      b4.z = B[(cc + 2) * 128 + k];
      b4.w = B[(cc + 3) * 128 + k];
    }
    float a0 = A[(r0 +  0) * 128 + k];
    float a1 = A[(r0 + 32) * 128 + k];
    float a2 = A[(r0 + 64) * 128 + k];
    float a3 = A[(r0 + 96) * 128 + k];
    acc0.x += a0 * b4.x; acc0.y += a0 * b4.y; acc0.z += a0 * b4.z; acc0.w += a0 * b4.w;
    acc1.x += a1 * b4.x; acc1.y += a1 * b4.y; acc1.z += a1 * b4.z; acc1.w += a1 * b4.w;
    acc2.x += a2 * b4.x; acc2.y += a2 * b4.y; acc2.z += a2 * b4.z; acc2.w += a2 * b4.w;
    acc3.x += a3 * b4.x; acc3.y += a3 * b4.y; acc3.z += a3 * b4.z; acc3.w += a3 * b4.w;
  }
  *(float4*)(C + (r0 +  0) * 128 + cc) = acc0;
  *(float4*)(C + (r0 + 32) * 128 + cc) = acc1;
  *(float4*)(C + (r0 + 64) * 128 + cc) = acc2;
  *(float4*)(C + (r0 + 96) * 128 + cc) = acc3;
}

// Fused: Wfw = W_fc[0:128]@W_w (blocks 0-3), Wc = W_pk@W_at^T (blocks 4-7), wcap (block 8)
__global__ __launch_bounds__(256) void prep_weights(
    const float* __restrict__ Wfc, const float* __restrict__ Ww,
    const float* __restrict__ Wpk, const float* __restrict__ Wat,
    float* __restrict__ Wfw, float* __restrict__ Wc, float* __restrict__ wcap)
{
  int blk = blockIdx.x, tid = threadIdx.x;
  if (blk == 8) {
    if (tid < 128) {
      float s = 0.f;
      for (int k = 0; k < 128; ++k) s += Wfc[128 * 128 + k] * Ww[k * 128 + tid];
      wcap[tid] = s;
    }
    return;
  }
  const float* A  = (blk < 4) ? Wfc : Wpk;
  const float* B  = (blk < 4) ? Ww  : Wat;
  float*       C  = (blk < 4) ? Wfw : Wc;
  int transB = (blk < 4) ? 0 : 1;
  int cb = blk & 3;
  int cc = cb * 32 + (tid & 7) * 4;
  int r0 = tid >> 3;
  float4 acc0 = {0,0,0,0}, acc1 = {0,0,0,0}, acc2 = {0,0,0,0}, acc3 = {0,0,0,0};
  for (int k = 0; k < 128; ++k) {
    float4 b4;
    if (!transB) {
      b4 = *(const float4*)(B + k * 128 + cc);
    } else {
      b4.x = B[(cc + 0) * 128 + k];
      b4.y = B[(cc + 1) * 128 + k];
      b4.z = B[(cc + 2) * 128 + k];
      b4.w = B[(cc + 3) * 128 + k];
    }
    float a0 = A[(r0 +  0) * 128 + k];
    float a1 = A[(r0 + 32) * 128 + k];
    float a2 = A[(r0 + 64) * 128 + k];
    float a3 = A[(r0 + 96) * 128 + k];
    acc0.x += a0 * b4.x; acc0.y += a0 * b4.y; acc0.z += a0 * b4.z; acc0.w += a0 * b4.w;
    acc1.x += a1 * b4.x; acc1.y += a1 * b4.y; acc1.z += a1 * b4.z; acc1.w += a1 * b4.w;
    acc2.x += a2 * b4.x; acc2.y += a2 * b4.y; acc2.z += a2 * b4.z; acc2.w += a2 * b4.w;
    acc3.x += a3 * b4.x; acc3.y += a3 * b4.y; acc3.z += a3 * b4.z; acc3.w += a3 * b4.w;
  }
  *(float4*)(C + (r0 +  0) * 128 + cc) = acc0;
  *(float4*)(C + (r0 + 32) * 128 + cc) = acc1;
  *(float4*)(C + (r0 + 64) * 128 + cc) = acc2;
  *(float4*)(C + (r0 + 96) * 128 + cc) = acc3;
}

// =====================================================================
// Decode: one block per batch row. 5 lgkm-only barriers per step, no
// global loads on the dependency chain (encW in LDS, Qpool prefetched).
// =====================================================================
__global__ __attribute__((amdgpu_flat_work_group_size(256, 256), amdgpu_waves_per_eu(2, 2)))
void decode_kernel(
    const float* __restrict__ enc,      // B,N,H
    const float* __restrict__ Wk,       // H,H
    const float* __restrict__ Wv,       // H,H
    const float* __restrict__ Wc,       // ws: W_pk @ W_attnfc^T
    const float* __restrict__ encW,     // ws: B,N,H
    const float* __restrict__ Qpool,    // ws: T,B,H
    const float* __restrict__ wcap,     // ws: H
    const float* __restrict__ capcity,  // B,1
    const float* __restrict__ demand,   // B,N
    float* __restrict__ out)            // [B*T actions as float][B logp]
{
  __shared__ __align__(16) float s_buf[N_ * 132];  // enc staging (pad 132) -> encW (stride 128)
  __shared__ __align__(16) float s_sc[8 * 104];
  __shared__ __align__(16) float s_Q[128];
  __shared__ __align__(16) float s_part[256];
  __shared__ __align__(16) float s_p2[256];

  const int b    = blockIdx.x;
  const int tid  = threadIdx.x;
  const int lane = tid & 63;
  const int wave = tid >> 6;
  const int an = tid & 127, aj = tid >> 7;   // role A: n row, dim half
  const int bj = tid & 127, bh = tid >> 7;   // role B: output dim, n half
  const float invSqrtH = 0.08838834764831845f;

  // ---- early scalar/global loads (off critical path) ----
  float cap  = capcity[b];
  float cap0 = capcity[0];
  float dem0 = demand[(long long)b * N_ + lane];
  float dem1 = (lane < 37) ? demand[(long long)b * N_ + 64 + lane] : 0.f;
  float wcr  = (tid < 128) ? wcap[tid] : 0.f;
  float qp0  = (tid < 128) ? Qpool[(long long)b * H_ + tid] : 0.f;

  // ---- stage enc[b] into LDS (row pad 132) ----
  for (int idx = tid; idx < N_ * 32; idx += 256) {
    int row = idx >> 5, q = idx & 31;
    float4 v = *(const float4*)(enc + ((long long)b * N_ + row) * H_ + q * 4);
    float* d = s_buf + row * 132 + q * 4;
    d[0] = v.x; d[1] = v.y; d[2] = v.z; d[3] = v.w;
  }
  BAR();

  // ---- V column slices: vreg[nl] = V[bh*51+nl][bj] ----
  float vreg[51];
#pragma unroll
  for (int q = 0; q < 51; ++q) vreg[q] = 0.f;
  {
    const int base = bh * 51;
    for (int i4 = 0; i4 < 32; ++i4) {
      float w0 = Wv[(i4 * 4 + 0) * H_ + bj];
      float w1 = Wv[(i4 * 4 + 1) * H_ + bj];
      float w2 = Wv[(i4 * 4 + 2) * H_ + bj];
      float w3 = Wv[(i4 * 4 + 3) * H_ + bj];
#pragma unroll
      for (int nl = 0; nl < 51; ++nl) {
        if (base + nl < N_) {
          float4 e = *(const float4*)(s_buf + (base + nl) * 132 + i4 * 4);
          vreg[nl] += e.x * w0 + e.y * w1 + e.z * w2 + e.w * w3;
        }
      }
    }
  }

  // ---- K and Kp2 (=P) row slices (role A) ----
  float kreg[64], preg[64];
#pragma unroll
  for (int q = 0; q < 64; ++q) { kreg[q] = 0.f; preg[q] = 0.f; }
  if (an < N_) {
    for (int i = 0; i < 128; ++i) {
      float e = s_buf[an * 132 + i];
      const float4* wk = (const float4*)(Wk + i * H_ + aj * 64);
      const float4* wc = (const float4*)(Wc + i * H_ + aj * 64);
#pragma unroll
      for (int q = 0; q < 16; ++q) {
        float4 a = wk[q];
        kreg[q * 4 + 0] += e * a.x; kreg[q * 4 + 1] += e * a.y;
        kreg[q * 4 + 2] += e * a.z; kreg[q * 4 + 3] += e * a.w;
        float4 c = wc[q];
        preg[q * 4 + 0] += e * c.x; preg[q * 4 + 1] += e * c.y;
        preg[q * 4 + 2] += e * c.z; preg[q * 4 + 3] += e * c.w;
      }
    }
  }
  BAR();  // all reads of s_buf(enc view) done

  // ---- overwrite s_buf with encW rows (stride 128) ----
  for (int idx = tid; idx < N_ * 32; idx += 256) {
    int row = idx >> 5, q = idx & 31;
    float4 v = *(const float4*)(encW + ((long long)b * N_ + row) * H_ + q * 4);
    float* d = s_buf + row * 128 + q * 4;
    d[0] = v.x; d[1] = v.y; d[2] = v.z; d[3] = v.w;
  }
  BAR();

  // ---- initial state (per-wave redundant, wave-uniform regs) ----
  unsigned long long m1lo = 1ull, m1hi = 0ull;
  {
    bool p0i = (lane == 0) || (dem0 > cap);
    bool p1i = (lane < 37) ? (dem1 > cap) : true;
    unsigned long long klo = __ballot(p0i);
    unsigned long long khi = __ballot(p1i) & M37;
    if (klo == ~0ull && khi == M37) klo &= ~1ull;
    m1lo = 1ull; m1hi = 0ull;
    // mask state lives below
    if (tid < 128) s_Q[tid] = s_buf[tid] + cap * wcr + qp0;  // Q_0 (idx=0)
    // store mask
    // (kept in registers msklo/mskhi declared next)
    asm volatile("" ::: );  // no-op
    // fallthrough
    // assign:
    // (declared after to keep scope simple)
    // -- see below
    // placeholders replaced by real vars:
    __shared__ int dummy_unused;
    (void)dummy_unused;
    // real assignment done outside this scope via variables:
    // handled below
    // (we just recompute here)
    // NOTE: recomputation below is identical
    (void)klo; (void)khi;
  }
  // recompute mask init cleanly (cheap, keeps variables in function scope)
  unsigned long long msklo, mskhi;
  {
    bool p0i = (lane == 0) || (dem0 > cap);
    bool p1i = (lane < 37) ? (dem1 > cap) : true;
    msklo = __ballot(p0i);
    mskhi = __ballot(p1i) & M37;
    if (msklo == ~0ull && mskhi == M37) msklo &= ~1ull;
  }
  bool  done = false;
  float logpAcc = 0.f;
  BAR();

  for (int t = 0; t < T_; ++t) {
    // prefetch Qpool row for t+1 (consumed in ph6; ~full step to hide latency)
    int tn = (t + 1 < T_) ? (t + 1) : t;
    float qp_nxt = (tid < 128) ? Qpool[((long long)tn * B_ + b) * H_ + tid] : 0.f;

    // ---- ph2: compat (role A), masked, *0.25 ----
    if (an < N_) {
      const float4* q4 = (const float4*)(s_Q + aj * 64);
      bool mb = (an < 64) ? ((msklo >> an) & 1ull) : ((mskhi >> (an - 64)) & 1ull);
#pragma unroll
      for (int h = 0; h < 4; ++h) {
        float c = 0.f;
#pragma unroll
        for (int q = 0; q < 4; ++q) {
          float4 qq = q4[h * 4 + q];
          c += qq.x * kreg[h * 16 + q * 4 + 0] + qq.y * kreg[h * 16 + q * 4 + 1]
             + qq.z * kreg[h * 16 + q * 4 + 2] + qq.w * kreg[h * 16 + q * 4 + 3];
        }
        s_sc[(aj * 4 + h) * 104 + an] = mb ? -INFINITY : 0.25f * c;
      }
    }
    BAR();

    // ---- ph3: softmax, wave w handles heads w and w+4 (interleaved) ----
    {
      float* r0 = s_sc + wave * 104;
      float* r1 = s_sc + (wave + 4) * 104;
      float a0 = r0[lane], a1 = r1[lane];
      float b0 = (lane < 37) ? r0[64 + lane] : -INFINITY;
      float b1 = (lane < 37) ? r1[64 + lane] : -INFINITY;
      float m0  = wave_max64(fmaxf(a0, b0));   // exact max (order-independent)
      float m1v = wave_max64(fmaxf(a1, b1));
      float ea0 = expf(a0 - m0),  eb0 = (lane < 37) ? expf(b0 - m0)  : 0.f;
      float ea1 = expf(a1 - m1v), eb1 = (lane < 37) ? expf(b1 - m1v) : 0.f;
      float s0 = ea0 + eb0, s1 = ea1 + eb1;
      // keep R1's exact butterfly order: bit-identical softmax denominators
#pragma unroll
      for (int off = 32; off > 0; off >>= 1) {
        s0 += __shfl_xor(s0, off);
        s1 += __shfl_xor(s1, off);
      }
      r0[lane] = ea0 / s0; r1[lane] = ea1 / s1;
      if (lane < 37) { r0[64 + lane] = eb0 / s0; r1[64 + lane] = eb1 / s1; }
    }
    BAR();

    // ---- ph4: glimpse partial (role B) ----
    {
      int h = bj >> 4;
      const float* srow = s_sc + h * 104;
      float acc = 0.f;
      if (bh == 0) {
#pragma unroll
        for (int q = 0; q < 12; ++q) {
          float4 sv = *(const float4*)(srow + q * 4);
          acc += sv.x * vreg[q * 4 + 0] + sv.y * vreg[q * 4 + 1]
               + sv.z * vreg[q * 4 + 2] + sv.w * vreg[q * 4 + 3];
        }
        acc += srow[48] * vreg[48] + srow[49] * vreg[49] + srow[50] * vreg[50];
      } else {
        acc += srow[51] * vreg[0];
#pragma unroll
        for (int q = 0; q < 12; ++q) {
          float4 sv = *(const float4*)(srow + 52 + q * 4);
          acc += sv.x * vreg[1 + q * 4] + sv.y * vreg[2 + q * 4]
               + sv.z * vreg[3 + q * 4] + sv.w * vreg[4 + q * 4];
        }
        acc += srow[100] * vreg[49];
      }
      s_part[bh * 128 + bj] = acc;
    }
    BAR();

    // ---- ph5: comp2 partial with inline glimpse-sum (role A) ----
    if (an < N_) {
      const float4* p0 = (const float4*)(s_part + aj * 64);
      const float4* p1 = (const float4*)(s_part + 128 + aj * 64);
      float c = 0.f;
#pragma unroll
      for (int q = 0; q < 16; ++q) {
        float4 g0 = p0[q], g1 = p1[q];
        float gx = g0.x + g1.x, gy = g0.y + g1.y, gz = g0.z + g1.z, gw = g0.w + g1.w;
        c += gx * preg[q * 4 + 0] + gy * preg[q * 4 + 1]
           + gz * preg[q * 4 + 2] + gw * preg[q * 4 + 3];
      }
      s_p2[aj * 128 + an] = c;
    }
    BAR();

    // ---- ph6: logits, argmax, lse, state update, next-Q (all waves redundant) ----
    {
      float l0 = -INFINITY, l1 = -INFINITY;
      bool mb0 = (msklo >> lane) & 1ull;
      if (!mb0) l0 = 10.f * tanhf((s_p2[lane] + s_p2[128 + lane]) * invSqrtH);
      if (lane < 37) {
        bool mb1 = (mskhi >> lane) & 1ull;
        if (!mb1) l1 = 10.f * tanhf((s_p2[64 + lane] + s_p2[192 + lane]) * invSqrtH);
      }
      float vmax = wave_max64(fmaxf(l0, l1));   // exact max
      unsigned long long blo = __ballot(l0 == vmax);
      unsigned long long bhi = __ballot(l1 == vmax);
      int amax = blo ? (__ffsll((long long)blo) - 1)
                     : (64 + __ffsll((long long)bhi) - 1);
      float ss = wave_sum64(expf(l0 - vmax) + expf(l1 - vmax));  // feeds log_p only
      if (!done) logpAcc -= logf(ss);

      // state update (update_state + update_mask)
      float dlo = __int_as_float(__builtin_amdgcn_readlane(__float_as_int(dem0), amax & 63));
      float dhi = __int_as_float(__builtin_amdgcn_readlane(__float_as_int(dem1), amax & 63));
      float capNew = (amax == 0) ? cap0 : (cap - ((amax < 64) ? dlo : dhi));
      if (amax < 64) m1lo |= (1ull << amax); else m1hi |= (1ull << (amax - 64));
      m1lo = (m1lo & ~1ull) | (unsigned long long)(amax == 0);
      done = ((int)__popcll(m1lo & ~1ull) + (int)__popcll(m1hi)) >= (N_ - 1);
      bool p0m = ((m1lo >> lane) & 1ull) || (dem0 > capNew);
      bool p1m = (lane < 37) ? (((mskhi = mskhi, m1hi >> lane) & 1ull) || (dem1 > capNew)) : true;
      unsigned long long klo = __ballot(p0m);
      unsigned long long khi = __ballot(p1m) & M37;
      if (klo == ~0ull && khi == M37) klo &= ~1ull;
      msklo = klo; mskhi = khi; cap = capNew;

      if (tid == 0) out[(long long)b * T_ + t] = (float)amax;
      // build Q_{t+1} (uses prefetched Qpool[t+1]); safe: s_Q last read before BAR after ph2
      if (tid < 128) s_Q[tid] = s_buf[amax * H_ + tid] + capNew * wcr + qp_nxt;
    }
    BAR();
  }

  if (tid == 0) out[(long long)B_ * T_ + b] = logpAcc;
}

// =====================================================================
extern "C" void kernel_launch(void* const* d_in, const int* in_sizes, int n_in,
                              void* d_out, int out_size, void* d_ws, size_t ws_size,
                              hipStream_t stream)
{
  const float* enc   = (const float*)d_in[0];
  const float* pool  = (const float*)d_in[1];
  const float* cap   = (const float*)d_in[3];
  const float* dem   = (const float*)d_in[4];
  const float* W_fc  = (const float*)d_in[7];   // 129x128
  const float* W_fc1 = (const float*)d_in[8];   // 128x128
  const float* W_w   = (const float*)d_in[9];
  const float* W_kk  = (const float*)d_in[10];
  const float* W_vv  = (const float*)d_in[11];
  const float* W_at  = (const float*)d_in[12];
  const float* W_pk  = (const float*)d_in[13];
  float* out = (float*)d_out;
  float* ws  = (float*)d_ws;

  // workspace layout (floats), ~81.7 MB (unchanged from R1)
  float* Mbuf  = ws;                               // 141 * 16384
  float* Abuf  = Mbuf + 141 * 16384;               // 140 * 16384
  float* Qpl   = Abuf + 140 * 16384;               // 140 * 512 * 128
  float* encW  = Qpl + 140 * 512 * 128;            // 512 * 101 * 128
  float* Wfw   = encW + 512 * 101 * 128;           // 16384
  float* Wc    = Wfw + 16384;                      // 16384
  float* wcapb = Wc + 16384;                       // 128

  hipMemcpyAsync(Mbuf + 16384, W_fc1, 128 * 128 * sizeof(float),
                 hipMemcpyDeviceToDevice, stream);
  prep_weights<<<9, 256, 0, stream>>>(W_fc, W_w, W_pk, W_at, Wfw, Wc, wcapb);
  // matrix powers by doubling: M[L+s] = M[s] @ M[L]
  for (int L = 1; L < 140; L <<= 1) {
    int cnt = (L < 140 - L) ? L : (140 - L);
    gemm_tile<<<dim3(4, cnt), 256, 0, stream>>>(
        Mbuf + 16384, 16384,
        Mbuf + (long long)L * 16384, 0,
        Mbuf + (long long)(L + 1) * 16384, 16384, 0);
  }
  // A_t = M[t+1] @ W_w
  gemm_tile<<<dim3(4, 140), 256, 0, stream>>>(Mbuf + 16384, 16384, W_w, 0, Abuf, 16384, 0);
  // Qpool[t] = pool @ A_t
  gemm_tile<<<dim3(16, 140), 256, 0, stream>>>(pool, 0, Abuf, 16384, Qpl, 65536, 0);
  // encW = enc @ Wfw
  gemm_tile<<<dim3(404 * 4, 1), 256, 0, stream>>>(enc, 0, Wfw, 0, encW, 0, 0);
  // fused 140-step decode
  decode_kernel<<<512, 256, 0, stream>>>(enc, W_kk, W_vv, Wc, encW, Qpl, wcapb, cap, dem, out);
}

// Round 5
// 1131.173 us; speedup vs baseline: 1.7430x; 1.5348x over previous
//
#include <hip/hip_runtime.h>
#include <math.h>

#define B_ 512
#define N_ 101
#define H_ 128
#define T_ 140
#define M37 0x1FFFFFFFFFull

// lgkm-only barrier: does NOT drain vmcnt (global prefetches stay in flight)
#define BAR() asm volatile("s_waitcnt lgkmcnt(0)\n\ts_barrier" ::: "memory")

// ---------------- DPP wave64 reductions ----------------
template <int CTRL, int RM>
__device__ __forceinline__ float dpp_max_step(float x) {
  int t = __builtin_amdgcn_update_dpp((int)0xFF800000, __float_as_int(x), CTRL, RM, 0xF, false);
  return fmaxf(x, __int_as_float(t));
}
template <int CTRL, int RM>
__device__ __forceinline__ float dpp_add_step(float x) {
  int t = __builtin_amdgcn_update_dpp(0, __float_as_int(x), CTRL, RM, 0xF, false);
  return x + __int_as_float(t);
}
__device__ __forceinline__ float wave_max64(float x) {
  x = dpp_max_step<0x111, 0xF>(x);
  x = dpp_max_step<0x112, 0xF>(x);
  x = dpp_max_step<0x114, 0xF>(x);
  x = dpp_max_step<0x118, 0xF>(x);
  x = dpp_max_step<0x142, 0xA>(x);
  x = dpp_max_step<0x143, 0xC>(x);
  return __int_as_float(__builtin_amdgcn_readlane(__float_as_int(x), 63));
}
__device__ __forceinline__ float wave_sum64(float x) {
  x = dpp_add_step<0x111, 0xF>(x);
  x = dpp_add_step<0x112, 0xF>(x);
  x = dpp_add_step<0x114, 0xF>(x);
  x = dpp_add_step<0x118, 0xF>(x);
  x = dpp_add_step<0x142, 0xA>(x);
  x = dpp_add_step<0x143, 0xC>(x);
  return __int_as_float(__builtin_amdgcn_readlane(__float_as_int(x), 63));
}

// ---------------- 128x32 GEMM tile (bit-identical to R2's gemm_tile) ----
__device__ __forceinline__ void gemm_tile_dev(
    const float* A, const float* B, float* C, int cb, int transB, int tid)
{
  int cc = cb * 32 + (tid & 7) * 4;
  int r0 = tid >> 3;
  float4 acc0 = {0,0,0,0}, acc1 = {0,0,0,0}, acc2 = {0,0,0,0}, acc3 = {0,0,0,0};
  for (int k = 0; k < 128; ++k) {
    float4 b4;
    if (!transB) {
      b4 = *(const float4*)(B + k * 128 + cc);
    } else {
      b4.x = B[(cc + 0) * 128 + k];
      b4.y = B[(cc + 1) * 128 + k];
      b4.z = B[(cc + 2) * 128 + k];
      b4.w = B[(cc + 3) * 128 + k];
    }
    float a0 = A[(r0 +  0) * 128 + k];
    float a1 = A[(r0 + 32) * 128 + k];
    float a2 = A[(r0 + 64) * 128 + k];
    float a3 = A[(r0 + 96) * 128 + k];
    acc0.x += a0 * b4.x; acc0.y += a0 * b4.y; acc0.z += a0 * b4.z; acc0.w += a0 * b4.w;
    acc1.x += a1 * b4.x; acc1.y += a1 * b4.y; acc1.z += a1 * b4.z; acc1.w += a1 * b4.w;
    acc2.x += a2 * b4.x; acc2.y += a2 * b4.y; acc2.z += a2 * b4.z; acc2.w += a2 * b4.w;
    acc3.x += a3 * b4.x; acc3.y += a3 * b4.y; acc3.z += a3 * b4.z; acc3.w += a3 * b4.w;
  }
  *(float4*)(C + (r0 +  0) * 128 + cc) = acc0;
  *(float4*)(C + (r0 + 32) * 128 + cc) = acc1;
  *(float4*)(C + (r0 + 64) * 128 + cc) = acc2;
  *(float4*)(C + (r0 + 96) * 128 + cc) = acc3;
}

// n1: Wfw(4) + Wc(4) + wcap(1) + M^2(4)
__global__ __launch_bounds__(256) void stage_a(
    const float* __restrict__ Wfc, const float* __restrict__ Ww,
    const float* __restrict__ Wpk, const float* __restrict__ Wat,
    const float* __restrict__ F,
    float* __restrict__ Wfw, float* __restrict__ Wc, float* __restrict__ wcap,
    float* __restrict__ Mbuf)
{
  int j = blockIdx.x, tid = threadIdx.x;
  if (j < 4)       gemm_tile_dev(Wfc, Ww, Wfw, j, 0, tid);
  else if (j < 8)  gemm_tile_dev(Wpk, Wat, Wc, j - 4, 1, tid);
  else if (j == 8) {
    if (tid < 128) {
      float s = 0.f;
      for (int k = 0; k < 128; ++k) s += Wfc[128 * 128 + k] * Ww[k * 128 + tid];
      wcap[tid] = s;
    }
  } else gemm_tile_dev(F, F, Mbuf + 2ll * 16384, j - 9, 0, tid);
}

// n2: chain L=2 (M^3,M^4 : 8 tiles) + encW (1616 tiles)
__global__ __launch_bounds__(256) void stage_b(
    const float* __restrict__ F, const float* __restrict__ enc,
    const float* __restrict__ Wfw, float* __restrict__ Mbuf,
    float* __restrict__ encW)
{
  int bx = blockIdx.x, tid = threadIdx.x;
  if (bx < 8) {
    int s = (bx >> 2) + 1, cb = bx & 3;
    const float* As = (s == 1) ? F : Mbuf + (long long)s * 16384;
    gemm_tile_dev(As, Mbuf + 2ll * 16384, Mbuf + (long long)(2 + s) * 16384, cb, 0, tid);
  } else {
    int jj = bx - 8, rb = jj >> 2, cb = jj & 3;
    gemm_tile_dev(enc + (long long)rb * 16384, Wfw, encW + (long long)rb * 16384, cb, 0, tid);
  }
}

// n3..n7: chain level L: M^{L+s} = M^s @ M^L, s=1..c (grid = 4c)
__global__ __launch_bounds__(256) void chainL(
    const float* __restrict__ F, float* __restrict__ Mbuf, int L)
{
  int bx = blockIdx.x, tid = threadIdx.x;
  int s = (bx >> 2) + 1, cb = bx & 3;
  const float* As = (s == 1) ? F : Mbuf + (long long)s * 16384;
  gemm_tile_dev(As, Mbuf + (long long)L * 16384, Mbuf + (long long)(L + s) * 16384, cb, 0, tid);
}

// n8: chain L=128 (48 tiles: M^129..M^140) + A_t for t=0..126 (508 tiles)
__global__ __launch_bounds__(256) void stage_n8(
    const float* __restrict__ F, const float* __restrict__ Ww,
    float* __restrict__ Mbuf, float* __restrict__ Abuf)
{
  int bx = blockIdx.x, tid = threadIdx.x;
  if (bx < 48) {
    int s = (bx >> 2) + 1, cb = bx & 3;
    const float* As = (s == 1) ? F : Mbuf + (long long)s * 16384;
    gemm_tile_dev(As, Mbuf + 128ll * 16384, Mbuf + (long long)(128 + s) * 16384, cb, 0, tid);
  } else {
    int jj = bx - 48, t = jj >> 2, cb = jj & 3;
    const float* Ms = (t == 0) ? F : Mbuf + (long long)(t + 1) * 16384;
    gemm_tile_dev(Ms, Ww, Abuf + (long long)t * 16384, cb, 0, tid);
  }
}

// n9: A_t for t=127..139 (52 tiles) + Qpool[t] for t=0..126 (2032 tiles)
__global__ __launch_bounds__(256) void stage_n9(
    const float* __restrict__ Ww, const float* __restrict__ pool,
    float* __restrict__ Mbuf, float* __restrict__ Abuf, float* __restrict__ Qpl)
{
  int bx = blockIdx.x, tid = threadIdx.x;
  if (bx < 52) {
    int t = 127 + (bx >> 2), cb = bx & 3;
    gemm_tile_dev(Mbuf + (long long)(t + 1) * 16384, Ww, Abuf + (long long)t * 16384, cb, 0, tid);
  } else {
    int jj = bx - 52, t = jj >> 4, sub = jj & 15, rb = sub >> 2, cb = sub & 3;
    gemm_tile_dev(pool + (long long)rb * 16384, Abuf + (long long)t * 16384,
                  Qpl + (long long)t * 65536 + (long long)rb * 16384, cb, 0, tid);
  }
}

// n10: Qpool[t] for t=127..139 (208 tiles)
__global__ __launch_bounds__(256) void stage_n10(
    const float* __restrict__ pool, float* __restrict__ Abuf, float* __restrict__ Qpl)
{
  int bx = blockIdx.x, tid = threadIdx.x;
  int t = 127 + (bx >> 4), sub = bx & 15, rb = sub >> 2, cb = sub & 3;
  gemm_tile_dev(pool + (long long)rb * 16384, Abuf + (long long)t * 16384,
                Qpl + (long long)t * 65536 + (long long)rb * 16384, cb, 0, tid);
}

// =====================================================================
// Decode: one block per batch row; 4 barriers/step (compat+softmax fused
// in-wave; all values bit-identical to the R2-verified trajectory).
// =====================================================================
__global__ __attribute__((amdgpu_flat_work_group_size(256, 256), amdgpu_waves_per_eu(2, 2)))
void decode_kernel(
    const float* __restrict__ enc,
    const float* __restrict__ Wk,
    const float* __restrict__ Wv,
    const float* __restrict__ Wc,
    const float* __restrict__ encW,
    const float* __restrict__ Qpool,
    const float* __restrict__ wcap,
    const float* __restrict__ capcity,
    const float* __restrict__ demand,
    float* __restrict__ out)
{
  __shared__ __align__(16) float s_buf[N_ * 132];  // enc (pad 132) -> encW (stride 128)
  __shared__ __align__(16) float s_sc[8 * 104];
  __shared__ __align__(16) float s_Q[128];
  __shared__ __align__(16) float s_part[256];
  __shared__ __align__(16) float s_p2[256];

  const int b    = blockIdx.x;
  const int tid  = threadIdx.x;
  const int lane = tid & 63;
  const int wave = tid >> 6;
  const int an = tid & 127, aj = tid >> 7;   // role A (comp2): n row, dim half
  const int bj = tid & 127, bh = tid >> 7;   // role B (glimpse): out dim, n half
  const float invSqrtH = 0.08838834764831845f;

  float cap  = capcity[b];
  float cap0 = capcity[0];
  float dem0 = demand[(long long)b * N_ + lane];
  float dem1 = (lane < 37) ? demand[(long long)b * N_ + 64 + lane] : 0.f;
  float wcr  = (tid < 128) ? wcap[tid] : 0.f;
  float qp0  = (tid < 128) ? Qpool[(long long)b * H_ + tid] : 0.f;

  // ---- stage enc[b] into LDS ----
  for (int idx = tid; idx < N_ * 32; idx += 256) {
    int row = idx >> 5, q = idx & 31;
    float4 v = *(const float4*)(enc + ((long long)b * N_ + row) * H_ + q * 4);
    float* d = s_buf + row * 132 + q * 4;
    d[0] = v.x; d[1] = v.y; d[2] = v.z; d[3] = v.w;
  }
  BAR();

  // ---- V column slices (role B): vreg[nl] = V[bh*51+nl][bj] ----
  float vreg[51];
#pragma unroll
  for (int q = 0; q < 51; ++q) vreg[q] = 0.f;
  {
    const int base = bh * 51;
    for (int i4 = 0; i4 < 32; ++i4) {
      float w0 = Wv[(i4 * 4 + 0) * H_ + bj];
      float w1 = Wv[(i4 * 4 + 1) * H_ + bj];
      float w2 = Wv[(i4 * 4 + 2) * H_ + bj];
      float w3 = Wv[(i4 * 4 + 3) * H_ + bj];
#pragma unroll
      for (int nl = 0; nl < 51; ++nl) {
        if (base + nl < N_) {
          float4 e = *(const float4*)(s_buf + (base + nl) * 132 + i4 * 4);
          vreg[nl] += e.x * w0 + e.y * w1 + e.z * w2 + e.w * w3;
        }
      }
    }
  }

  // ---- K rows, per-wave layout: lane l of wave w holds
  //      K[l][w*16..], K[l][(w+4)*16..], K[64+l][w*16..], K[64+l][(w+4)*16..] ----
  float kreg[64];
#pragma unroll
  for (int q = 0; q < 64; ++q) kreg[q] = 0.f;
  {
    const int n0 = lane;
    const int n1c = (lane < 37) ? 64 + lane : 0;   // lanes>=37: dummy (results unused)
    for (int i = 0; i < 128; ++i) {
      float e0 = s_buf[n0 * 132 + i];
      float e1 = s_buf[n1c * 132 + i];
      const float4* wk0 = (const float4*)(Wk + i * H_ + wave * 16);
      const float4* wk1 = (const float4*)(Wk + i * H_ + (wave + 4) * 16);
#pragma unroll
      for (int q = 0; q < 4; ++q) {
        float4 a = wk0[q];
        kreg[q * 4 + 0] += e0 * a.x; kreg[q * 4 + 1] += e0 * a.y;
        kreg[q * 4 + 2] += e0 * a.z; kreg[q * 4 + 3] += e0 * a.w;
        kreg[32 + q * 4 + 0] += e1 * a.x; kreg[32 + q * 4 + 1] += e1 * a.y;
        kreg[32 + q * 4 + 2] += e1 * a.z; kreg[32 + q * 4 + 3] += e1 * a.w;
        float4 c = wk1[q];
        kreg[16 + q * 4 + 0] += e0 * c.x; kreg[16 + q * 4 + 1] += e0 * c.y;
        kreg[16 + q * 4 + 2] += e0 * c.z; kreg[16 + q * 4 + 3] += e0 * c.w;
        kreg[48 + q * 4 + 0] += e1 * c.x; kreg[48 + q * 4 + 1] += e1 * c.y;
        kreg[48 + q * 4 + 2] += e1 * c.z; kreg[48 + q * 4 + 3] += e1 * c.w;
      }
    }
  }

  // ---- P rows (role A, old layout): preg = Kp2[an][aj*64 .. +64] ----
  float preg[64];
#pragma unroll
  for (int q = 0; q < 64; ++q) preg[q] = 0.f;
  if (an < N_) {
    for (int i = 0; i < 128; ++i) {
      float e = s_buf[an * 132 + i];
      const float4* wc = (const float4*)(Wc + i * H_ + aj * 64);
#pragma unroll
      for (int q = 0; q < 16; ++q) {
        float4 c = wc[q];
        preg[q * 4 + 0] += e * c.x; preg[q * 4 + 1] += e * c.y;
        preg[q * 4 + 2] += e * c.z; preg[q * 4 + 3] += e * c.w;
      }
    }
  }
  BAR();

  // ---- overwrite s_buf with encW rows (stride 128) ----
  for (int idx = tid; idx < N_ * 32; idx += 256) {
    int row = idx >> 5, q = idx & 31;
    float4 v = *(const float4*)(encW + ((long long)b * N_ + row) * H_ + q * 4);
    float* d = s_buf + row * 128 + q * 4;
    d[0] = v.x; d[1] = v.y; d[2] = v.z; d[3] = v.w;
  }
  BAR();

  // ---- initial mask + Q_0 ----
  unsigned long long m1lo = 1ull, m1hi = 0ull;
  unsigned long long msklo, mskhi;
  {
    bool p0i = (lane == 0) || (dem0 > cap);
    bool p1i = (lane < 37) ? (dem1 > cap) : true;
    msklo = __ballot(p0i);
    mskhi = __ballot(p1i) & M37;
    if (msklo == ~0ull && mskhi == M37) msklo &= ~1ull;
  }
  if (tid < 128) s_Q[tid] = s_buf[tid] + cap * wcr + qp0;
  bool  done = false;
  float logpAcc = 0.f;
  BAR();

  for (int t = 0; t < T_; ++t) {
    int tn = (t + 1 < T_) ? (t + 1) : t;
    float qp_nxt = (tid < 128) ? Qpool[((long long)tn * B_ + b) * H_ + tid] : 0.f;

    // ---- fused compat + softmax (in-wave; heads wave, wave+4) ----
    {
      const float4* q0 = (const float4*)(s_Q + wave * 16);
      const float4* q1 = (const float4*)(s_Q + (wave + 4) * 16);
      float c00 = 0.f, c01 = 0.f, c10 = 0.f, c11 = 0.f;
#pragma unroll
      for (int q = 0; q < 4; ++q) {
        float4 qq = q0[q];
        c00 += qq.x * kreg[q * 4 + 0] + qq.y * kreg[q * 4 + 1]
             + qq.z * kreg[q * 4 + 2] + qq.w * kreg[q * 4 + 3];
        c10 += qq.x * kreg[32 + q * 4 + 0] + qq.y * kreg[32 + q * 4 + 1]
             + qq.z * kreg[32 + q * 4 + 2] + qq.w * kreg[32 + q * 4 + 3];
        float4 qr = q1[q];
        c01 += qr.x * kreg[16 + q * 4 + 0] + qr.y * kreg[16 + q * 4 + 1]
             + qr.z * kreg[16 + q * 4 + 2] + qr.w * kreg[16 + q * 4 + 3];
        c11 += qr.x * kreg[48 + q * 4 + 0] + qr.y * kreg[48 + q * 4 + 1]
             + qr.z * kreg[48 + q * 4 + 2] + qr.w * kreg[48 + q * 4 + 3];
      }
      bool mb0 = (msklo >> lane) & 1ull;
      bool mb1v = (lane < 37) ? ((mskhi >> lane) & 1ull) : true;
      float a0 = mb0 ? -INFINITY : 0.25f * c00;
      float a1 = mb0 ? -INFINITY : 0.25f * c01;
      float b0 = mb1v ? -INFINITY : 0.25f * c10;
      float b1 = mb1v ? -INFINITY : 0.25f * c11;

      float m0  = wave_max64(fmaxf(a0, b0));
      float m1v = wave_max64(fmaxf(a1, b1));
      float ea0 = expf(a0 - m0),  eb0 = (lane < 37) ? expf(b0 - m0)  : 0.f;
      float ea1 = expf(a1 - m1v), eb1 = (lane < 37) ? expf(b1 - m1v) : 0.f;
      float s0 = ea0 + eb0, s1 = ea1 + eb1;
#pragma unroll
      for (int off = 32; off > 0; off >>= 1) {
        s0 += __shfl_xor(s0, off);
        s1 += __shfl_xor(s1, off);
      }
      float* r0 = s_sc + wave * 104;
      float* r1 = s_sc + (wave + 4) * 104;
      r0[lane] = ea0 / s0; r1[lane] = ea1 / s1;
      if (lane < 37) { r0[64 + lane] = eb0 / s0; r1[64 + lane] = eb1 / s1; }
    }
    BAR();

    // ---- glimpse partial (role B) ----
    {
      int h = bj >> 4;
      const float* srow = s_sc + h * 104;
      float acc = 0.f;
      if (bh == 0) {
#pragma unroll
        for (int q = 0; q < 12; ++q) {
          float4 sv = *(const float4*)(srow + q * 4);
          acc += sv.x * vreg[q * 4 + 0] + sv.y * vreg[q * 4 + 1]
               + sv.z * vreg[q * 4 + 2] + sv.w * vreg[q * 4 + 3];
        }
        acc += srow[48] * vreg[48] + srow[49] * vreg[49] + srow[50] * vreg[50];
      } else {
        acc += srow[51] * vreg[0];
#pragma unroll
        for (int q = 0; q < 12; ++q) {
          float4 sv = *(const float4*)(srow + 52 + q * 4);
          acc += sv.x * vreg[1 + q * 4] + sv.y * vreg[2 + q * 4]
               + sv.z * vreg[3 + q * 4] + sv.w * vreg[4 + q * 4];
        }
        acc += srow[100] * vreg[49];
      }
      s_part[bh * 128 + bj] = acc;
    }
    BAR();

    // ---- comp2 partial (role A) ----
    if (an < N_) {
      const float4* p0 = (const float4*)(s_part + aj * 64);
      const float4* p1 = (const float4*)(s_part + 128 + aj * 64);
      float c = 0.f;
#pragma unroll
      for (int q = 0; q < 16; ++q) {
        float4 g0 = p0[q], g1 = p1[q];
        float gx = g0.x + g1.x, gy = g0.y + g1.y, gz = g0.z + g1.z, gw = g0.w + g1.w;
        c += gx * preg[q * 4 + 0] + gy * preg[q * 4 + 1]
           + gz * preg[q * 4 + 2] + gw * preg[q * 4 + 3];
      }
      s_p2[aj * 128 + an] = c;
    }
    BAR();

    // ---- logits, argmax, lse, state, next Q ----
    {
      float l0 = -INFINITY, l1 = -INFINITY;
      bool mb0 = (msklo >> lane) & 1ull;
      if (!mb0) l0 = 10.f * tanhf((s_p2[lane] + s_p2[128 + lane]) * invSqrtH);
      if (lane < 37) {
        bool mb1 = (mskhi >> lane) & 1ull;
        if (!mb1) l1 = 10.f * tanhf((s_p2[64 + lane] + s_p2[192 + lane]) * invSqrtH);
      }
      float vmax = wave_max64(fmaxf(l0, l1));
      unsigned long long blo = __ballot(l0 == vmax);
      unsigned long long bhi = __ballot(l1 == vmax);
      int amax = blo ? (__ffsll((long long)blo) - 1)
                     : (64 + __ffsll((long long)bhi) - 1);
      float ss = wave_sum64(expf(l0 - vmax) + expf(l1 - vmax));
      if (!done) logpAcc -= logf(ss);

      float dlo = __int_as_float(__builtin_amdgcn_readlane(__float_as_int(dem0), amax & 63));
      float dhi = __int_as_float(__builtin_amdgcn_readlane(__float_as_int(dem1), amax & 63));
      float capNew = (amax == 0) ? cap0 : (cap - ((amax < 64) ? dlo : dhi));
      if (amax < 64) m1lo |= (1ull << amax); else m1hi |= (1ull << (amax - 64));
      m1lo = (m1lo & ~1ull) | (unsigned long long)(amax == 0);
      done = ((int)__popcll(m1lo & ~1ull) + (int)__popcll(m1hi)) >= (N_ - 1);
      bool p0m = ((m1lo >> lane) & 1ull) || (dem0 > capNew);
      bool p1m = (lane < 37) ? (((m1hi >> lane) & 1ull) || (dem1 > capNew)) : true;
      unsigned long long klo = __ballot(p0m);
      unsigned long long khi = __ballot(p1m) & M37;
      if (klo == ~0ull && khi == M37) klo &= ~1ull;
      msklo = klo; mskhi = khi; cap = capNew;

      if (tid == 0) out[(long long)b * T_ + t] = (float)amax;
      if (tid < 128) s_Q[tid] = s_buf[amax * H_ + tid] + capNew * wcr + qp_nxt;
    }
    BAR();
  }

  if (tid == 0) out[(long long)B_ * T_ + b] = logpAcc;
}

// =====================================================================
extern "C" void kernel_launch(void* const* d_in, const int* in_sizes, int n_in,
                              void* d_out, int out_size, void* d_ws, size_t ws_size,
                              hipStream_t stream)
{
  const float* enc   = (const float*)d_in[0];
  const float* pool  = (const float*)d_in[1];
  const float* cap   = (const float*)d_in[3];
  const float* dem   = (const float*)d_in[4];
  const float* W_fc  = (const float*)d_in[7];   // 129x128
  const float* W_fc1 = (const float*)d_in[8];   // 128x128 (= F)
  const float* W_w   = (const float*)d_in[9];
  const float* W_kk  = (const float*)d_in[10];
  const float* W_vv  = (const float*)d_in[11];
  const float* W_at  = (const float*)d_in[12];
  const float* W_pk  = (const float*)d_in[13];
  float* out = (float*)d_out;
  float* ws  = (float*)d_ws;

  float* Mbuf  = ws;                               // 141 * 16384 (slots 2..140 used)
  float* Abuf  = Mbuf + 141 * 16384;               // 140 * 16384
  float* Qpl   = Abuf + 140 * 16384;               // 140 * 512 * 128
  float* encW  = Qpl + 140 * 512 * 128;            // 512 * 101 * 128
  float* Wfw   = encW + 512 * 101 * 128;           // 16384
  float* Wc    = Wfw + 16384;                      // 16384
  float* wcapb = Wc + 16384;                       // 128

  stage_a<<<13, 256, 0, stream>>>(W_fc, W_w, W_pk, W_at, W_fc1, Wfw, Wc, wcapb, Mbuf);
  stage_b<<<1624, 256, 0, stream>>>(W_fc1, enc, Wfw, Mbuf, encW);
  chainL<<<16, 256, 0, stream>>>(W_fc1, Mbuf, 4);
  chainL<<<32, 256, 0, stream>>>(W_fc1, Mbuf, 8);
  chainL<<<64, 256, 0, stream>>>(W_fc1, Mbuf, 16);
  chainL<<<128, 256, 0, stream>>>(W_fc1, Mbuf, 32);
  chainL<<<256, 256, 0, stream>>>(W_fc1, Mbuf, 64);
  stage_n8<<<556, 256, 0, stream>>>(W_fc1, W_w, Mbuf, Abuf);
  stage_n9<<<2084, 256, 0, stream>>>(W_w, pool, Mbuf, Abuf, Qpl);
  stage_n10<<<208, 256, 0, stream>>>(pool, Abuf, Qpl);
  decode_kernel<<<512, 256, 0, stream>>>(enc, W_kk, W_vv, Wc, encW, Qpl, wcapb, cap, dem, out);
}

// Round 6
// 1052.066 us; speedup vs baseline: 1.8740x; 1.0752x over previous
//
#include <hip/hip_runtime.h>
#include <math.h>

#define B_ 512
#define N_ 101
#define H_ 128
#define T_ 140
#define M37 0x1FFFFFFFFFull

// lgkm-only barrier: does NOT drain vmcnt (global prefetches stay in flight)
#define BAR() asm volatile("s_waitcnt lgkmcnt(0)\n\ts_barrier" ::: "memory")

// ---------------- DPP wave64 reductions ----------------
template <int CTRL, int RM>
__device__ __forceinline__ float dpp_max_step(float x) {
  int t = __builtin_amdgcn_update_dpp((int)0xFF800000, __float_as_int(x), CTRL, RM, 0xF, false);
  return fmaxf(x, __int_as_float(t));
}
template <int CTRL, int RM>
__device__ __forceinline__ float dpp_add_step(float x) {
  int t = __builtin_amdgcn_update_dpp(0, __float_as_int(x), CTRL, RM, 0xF, false);
  return x + __int_as_float(t);
}
__device__ __forceinline__ float wave_max64(float x) {
  x = dpp_max_step<0x111, 0xF>(x);
  x = dpp_max_step<0x112, 0xF>(x);
  x = dpp_max_step<0x114, 0xF>(x);
  x = dpp_max_step<0x118, 0xF>(x);
  x = dpp_max_step<0x142, 0xA>(x);
  x = dpp_max_step<0x143, 0xC>(x);
  return __int_as_float(__builtin_amdgcn_readlane(__float_as_int(x), 63));
}
__device__ __forceinline__ float wave_sum64(float x) {
  x = dpp_add_step<0x111, 0xF>(x);
  x = dpp_add_step<0x112, 0xF>(x);
  x = dpp_add_step<0x114, 0xF>(x);
  x = dpp_add_step<0x118, 0xF>(x);
  x = dpp_add_step<0x142, 0xA>(x);
  x = dpp_add_step<0x143, 0xC>(x);
  return __int_as_float(__builtin_amdgcn_readlane(__float_as_int(x), 63));
}

// ---------------- 128x32 GEMM tile (bit-identical to R2's gemm_tile) ----
__device__ __forceinline__ void gemm_tile_dev(
    const float* A, const float* B, float* C, int cb, int transB, int tid)
{
  int cc = cb * 32 + (tid & 7) * 4;
  int r0 = tid >> 3;
  float4 acc0 = {0,0,0,0}, acc1 = {0,0,0,0}, acc2 = {0,0,0,0}, acc3 = {0,0,0,0};
  for (int k = 0; k < 128; ++k) {
    float4 b4;
    if (!transB) {
      b4 = *(const float4*)(B + k * 128 + cc);
    } else {
      b4.x = B[(cc + 0) * 128 + k];
      b4.y = B[(cc + 1) * 128 + k];
      b4.z = B[(cc + 2) * 128 + k];
      b4.w = B[(cc + 3) * 128 + k];
    }
    float a0 = A[(r0 +  0) * 128 + k];
    float a1 = A[(r0 + 32) * 128 + k];
    float a2 = A[(r0 + 64) * 128 + k];
    float a3 = A[(r0 + 96) * 128 + k];
    acc0.x += a0 * b4.x; acc0.y += a0 * b4.y; acc0.z += a0 * b4.z; acc0.w += a0 * b4.w;
    acc1.x += a1 * b4.x; acc1.y += a1 * b4.y; acc1.z += a1 * b4.z; acc1.w += a1 * b4.w;
    acc2.x += a2 * b4.x; acc2.y += a2 * b4.y; acc2.z += a2 * b4.z; acc2.w += a2 * b4.w;
    acc3.x += a3 * b4.x; acc3.y += a3 * b4.y; acc3.z += a3 * b4.z; acc3.w += a3 * b4.w;
  }
  *(float4*)(C + (r0 +  0) * 128 + cc) = acc0;
  *(float4*)(C + (r0 + 32) * 128 + cc) = acc1;
  *(float4*)(C + (r0 + 64) * 128 + cc) = acc2;
  *(float4*)(C + (r0 + 96) * 128 + cc) = acc3;
}

// n1: Wfw(4) + Wc(4) + wcap(1) + M^2(4)
__global__ __launch_bounds__(256) void stage_a(
    const float* __restrict__ Wfc, const float* __restrict__ Ww,
    const float* __restrict__ Wpk, const float* __restrict__ Wat,
    const float* __restrict__ F,
    float* __restrict__ Wfw, float* __restrict__ Wc, float* __restrict__ wcap,
    float* __restrict__ Mbuf)
{
  int j = blockIdx.x, tid = threadIdx.x;
  if (j < 4)       gemm_tile_dev(Wfc, Ww, Wfw, j, 0, tid);
  else if (j < 8)  gemm_tile_dev(Wpk, Wat, Wc, j - 4, 1, tid);
  else if (j == 8) {
    if (tid < 128) {
      float s = 0.f;
      for (int k = 0; k < 128; ++k) s += Wfc[128 * 128 + k] * Ww[k * 128 + tid];
      wcap[tid] = s;
    }
  } else gemm_tile_dev(F, F, Mbuf + 2ll * 16384, j - 9, 0, tid);
}

// n2: chain L=2 (M^3,M^4 : 8 tiles) + encW (1616 tiles)
__global__ __launch_bounds__(256) void stage_b(
    const float* __restrict__ F, const float* __restrict__ enc,
    const float* __restrict__ Wfw, float* __restrict__ Mbuf,
    float* __restrict__ encW)
{
  int bx = blockIdx.x, tid = threadIdx.x;
  if (bx < 8) {
    int s = (bx >> 2) + 1, cb = bx & 3;
    const float* As = (s == 1) ? F : Mbuf + (long long)s * 16384;
    gemm_tile_dev(As, Mbuf + 2ll * 16384, Mbuf + (long long)(2 + s) * 16384, cb, 0, tid);
  } else {
    int jj = bx - 8, rb = jj >> 2, cb = jj & 3;
    gemm_tile_dev(enc + (long long)rb * 16384, Wfw, encW + (long long)rb * 16384, cb, 0, tid);
  }
}

// n3..n7: chain level L: M^{L+s} = M^s @ M^L, s=1..c (grid = 4c)
__global__ __launch_bounds__(256) void chainL(
    const float* __restrict__ F, float* __restrict__ Mbuf, int L)
{
  int bx = blockIdx.x, tid = threadIdx.x;
  int s = (bx >> 2) + 1, cb = bx & 3;
  const float* As = (s == 1) ? F : Mbuf + (long long)s * 16384;
  gemm_tile_dev(As, Mbuf + (long long)L * 16384, Mbuf + (long long)(L + s) * 16384, cb, 0, tid);
}

// n8: chain L=128 (48 tiles: M^129..M^140) + A_t for t=0..126 (508 tiles)
__global__ __launch_bounds__(256) void stage_n8(
    const float* __restrict__ F, const float* __restrict__ Ww,
    float* __restrict__ Mbuf, float* __restrict__ Abuf)
{
  int bx = blockIdx.x, tid = threadIdx.x;
  if (bx < 48) {
    int s = (bx >> 2) + 1, cb = bx & 3;
    const float* As = (s == 1) ? F : Mbuf + (long long)s * 16384;
    gemm_tile_dev(As, Mbuf + 128ll * 16384, Mbuf + (long long)(128 + s) * 16384, cb, 0, tid);
  } else {
    int jj = bx - 48, t = jj >> 2, cb = jj & 3;
    const float* Ms = (t == 0) ? F : Mbuf + (long long)(t + 1) * 16384;
    gemm_tile_dev(Ms, Ww, Abuf + (long long)t * 16384, cb, 0, tid);
  }
}

// n9: A_t for t=127..139 (52 tiles) + Qpool[t] for t=0..126 (2032 tiles)
__global__ __launch_bounds__(256) void stage_n9(
    const float* __restrict__ Ww, const float* __restrict__ pool,
    float* __restrict__ Mbuf, float* __restrict__ Abuf, float* __restrict__ Qpl)
{
  int bx = blockIdx.x, tid = threadIdx.x;
  if (bx < 52) {
    int t = 127 + (bx >> 2), cb = bx & 3;
    gemm_tile_dev(Mbuf + (long long)(t + 1) * 16384, Ww, Abuf + (long long)t * 16384, cb, 0, tid);
  } else {
    int jj = bx - 52, t = jj >> 4, sub = jj & 15, rb = sub >> 2, cb = sub & 3;
    gemm_tile_dev(pool + (long long)rb * 16384, Abuf + (long long)t * 16384,
                  Qpl + (long long)t * 65536 + (long long)rb * 16384, cb, 0, tid);
  }
}

// n10: Qpool[t] for t=127..139 (208 tiles)
__global__ __launch_bounds__(256) void stage_n10(
    const float* __restrict__ pool, float* __restrict__ Abuf, float* __restrict__ Qpl)
{
  int bx = blockIdx.x, tid = threadIdx.x;
  int t = 127 + (bx >> 4), sub = bx & 15, rb = sub >> 2, cb = sub & 3;
  gemm_tile_dev(pool + (long long)rb * 16384, Abuf + (long long)t * 16384,
                Qpl + (long long)t * 65536 + (long long)rb * 16384, cb, 0, tid);
}

// ---------------- fused Q-build + compat + softmax (per-wave, no block barrier)
// Values are bit-identical to R5's ph_a fed by R5's s_Q build.
__device__ __forceinline__ void compat_softmax(
    int wave, int lane, int amaxU, float capU,
    unsigned long long msklo, unsigned long long mskhi,
    const float* s_buf, const float* s_wc, const float* s_qp,
    float* s_qs, const float* kreg, float* s_sc)
{
  if (lane < 32) {
    int d = (lane < 16) ? (wave * 16 + lane) : ((wave + 4) * 16 + (lane - 16));
    float qv = s_buf[amaxU * H_ + d] + capU * s_wc[d] + s_qp[d];
    s_qs[wave * 32 + lane] = qv;
  }
  asm volatile("s_waitcnt lgkmcnt(0)" ::: "memory");
  const float4* q0 = (const float4*)(s_qs + wave * 32);
  const float4* q1 = (const float4*)(s_qs + wave * 32 + 16);
  float c00 = 0.f, c01 = 0.f, c10 = 0.f, c11 = 0.f;
#pragma unroll
  for (int q = 0; q < 4; ++q) {
    float4 qq = q0[q];
    c00 += qq.x * kreg[q * 4 + 0] + qq.y * kreg[q * 4 + 1]
         + qq.z * kreg[q * 4 + 2] + qq.w * kreg[q * 4 + 3];
    c10 += qq.x * kreg[32 + q * 4 + 0] + qq.y * kreg[32 + q * 4 + 1]
         + qq.z * kreg[32 + q * 4 + 2] + qq.w * kreg[32 + q * 4 + 3];
    float4 qr = q1[q];
    c01 += qr.x * kreg[16 + q * 4 + 0] + qr.y * kreg[16 + q * 4 + 1]
         + qr.z * kreg[16 + q * 4 + 2] + qr.w * kreg[16 + q * 4 + 3];
    c11 += qr.x * kreg[48 + q * 4 + 0] + qr.y * kreg[48 + q * 4 + 1]
         + qr.z * kreg[48 + q * 4 + 2] + qr.w * kreg[48 + q * 4 + 3];
  }
  bool mb0 = (msklo >> lane) & 1ull;
  bool mb1v = (lane < 37) ? ((mskhi >> lane) & 1ull) : true;
  float a0 = mb0 ? -INFINITY : 0.25f * c00;
  float a1 = mb0 ? -INFINITY : 0.25f * c01;
  float b0 = mb1v ? -INFINITY : 0.25f * c10;
  float b1 = mb1v ? -INFINITY : 0.25f * c11;

  float m0  = wave_max64(fmaxf(a0, b0));
  float m1v = wave_max64(fmaxf(a1, b1));
  float ea0 = expf(a0 - m0),  eb0 = (lane < 37) ? expf(b0 - m0)  : 0.f;
  float ea1 = expf(a1 - m1v), eb1 = (lane < 37) ? expf(b1 - m1v) : 0.f;
  float s0 = ea0 + eb0, s1 = ea1 + eb1;
#pragma unroll
  for (int off = 32; off > 0; off >>= 1) {
    s0 += __shfl_xor(s0, off);
    s1 += __shfl_xor(s1, off);
  }
  float* r0 = s_sc + wave * 104;
  float* r1 = s_sc + (wave + 4) * 104;
  r0[lane] = ea0 / s0; r1[lane] = ea1 / s1;
  if (lane < 37) { r0[64 + lane] = eb0 / s0; r1[64 + lane] = eb1 / s1; }
}

// =====================================================================
// Decode: one block per batch row; 3 barriers/step; early exit on done.
// =====================================================================
__global__ __attribute__((amdgpu_flat_work_group_size(256, 256), amdgpu_waves_per_eu(2, 2)))
void decode_kernel(
    const float* __restrict__ enc,
    const float* __restrict__ Wk,
    const float* __restrict__ Wv,
    const float* __restrict__ Wc,
    const float* __restrict__ encW,
    const float* __restrict__ Qpool,
    const float* __restrict__ wcap,
    const float* __restrict__ capcity,
    const float* __restrict__ demand,
    float* __restrict__ out)
{
  __shared__ __align__(16) float s_buf[N_ * 132];  // enc (pad 132) -> encW (stride 128)
  __shared__ __align__(16) float s_sc[8 * 104];
  __shared__ __align__(16) float s_part[256];
  __shared__ __align__(16) float s_p2[256];
  __shared__ __align__(16) float s_qs[128];        // per-wave Q scratch (4 x 32)
  __shared__ __align__(16) float s_wc[128];
  __shared__ __align__(16) float s_qp[128];

  const int b    = blockIdx.x;
  const int tid  = threadIdx.x;
  const int lane = tid & 63;
  const int wave = tid >> 6;
  const int an = tid & 127, aj = tid >> 7;   // role A (comp2): n row, dim half
  const int bj = tid & 127, bh = tid >> 7;   // role B (glimpse): out dim, n half
  const float invSqrtH = 0.08838834764831845f;

  float cap  = capcity[b];
  float cap0 = capcity[0];
  float dem0 = demand[(long long)b * N_ + lane];
  float dem1 = (lane < 37) ? demand[(long long)b * N_ + 64 + lane] : 0.f;
  float wcr  = (tid < 128) ? wcap[tid] : 0.f;
  float qp0  = (tid < 128) ? Qpool[(long long)b * H_ + tid] : 0.f;

  // ---- stage enc[b] into LDS (pad 132) ----
  for (int idx = tid; idx < N_ * 32; idx += 256) {
    int row = idx >> 5, q = idx & 31;
    float4 v = *(const float4*)(enc + ((long long)b * N_ + row) * H_ + q * 4);
    float* d = s_buf + row * 132 + q * 4;
    d[0] = v.x; d[1] = v.y; d[2] = v.z; d[3] = v.w;
  }
  BAR();

  // ---- V column slices (role B): vreg[nl] = V[bh*51+nl][bj] ----
  float vreg[51];
#pragma unroll
  for (int q = 0; q < 51; ++q) vreg[q] = 0.f;
  {
    const int base = bh * 51;
    for (int i4 = 0; i4 < 32; ++i4) {
      float w0 = Wv[(i4 * 4 + 0) * H_ + bj];
      float w1 = Wv[(i4 * 4 + 1) * H_ + bj];
      float w2 = Wv[(i4 * 4 + 2) * H_ + bj];
      float w3 = Wv[(i4 * 4 + 3) * H_ + bj];
#pragma unroll
      for (int nl = 0; nl < 51; ++nl) {
        if (base + nl < N_) {
          float4 e = *(const float4*)(s_buf + (base + nl) * 132 + i4 * 4);
          vreg[nl] += e.x * w0 + e.y * w1 + e.z * w2 + e.w * w3;
        }
      }
    }
  }

  // ---- K rows, per-wave layout (as R5) ----
  float kreg[64];
#pragma unroll
  for (int q = 0; q < 64; ++q) kreg[q] = 0.f;
  {
    const int n0 = lane;
    const int n1c = (lane < 37) ? 64 + lane : 0;
    for (int i = 0; i < 128; ++i) {
      float e0 = s_buf[n0 * 132 + i];
      float e1 = s_buf[n1c * 132 + i];
      const float4* wk0 = (const float4*)(Wk + i * H_ + wave * 16);
      const float4* wk1 = (const float4*)(Wk + i * H_ + (wave + 4) * 16);
#pragma unroll
      for (int q = 0; q < 4; ++q) {
        float4 a = wk0[q];
        kreg[q * 4 + 0] += e0 * a.x; kreg[q * 4 + 1] += e0 * a.y;
        kreg[q * 4 + 2] += e0 * a.z; kreg[q * 4 + 3] += e0 * a.w;
        kreg[32 + q * 4 + 0] += e1 * a.x; kreg[32 + q * 4 + 1] += e1 * a.y;
        kreg[32 + q * 4 + 2] += e1 * a.z; kreg[32 + q * 4 + 3] += e1 * a.w;
        float4 c = wk1[q];
        kreg[16 + q * 4 + 0] += e0 * c.x; kreg[16 + q * 4 + 1] += e0 * c.y;
        kreg[16 + q * 4 + 2] += e0 * c.z; kreg[16 + q * 4 + 3] += e0 * c.w;
        kreg[48 + q * 4 + 0] += e1 * c.x; kreg[48 + q * 4 + 1] += e1 * c.y;
        kreg[48 + q * 4 + 2] += e1 * c.z; kreg[48 + q * 4 + 3] += e1 * c.w;
      }
    }
  }

  // ---- P rows (role A): preg = Kp2[an][aj*64 .. +64] ----
  float preg[64];
#pragma unroll
  for (int q = 0; q < 64; ++q) preg[q] = 0.f;
  if (an < N_) {
    for (int i = 0; i < 128; ++i) {
      float e = s_buf[an * 132 + i];
      const float4* wc = (const float4*)(Wc + i * H_ + aj * 64);
#pragma unroll
      for (int q = 0; q < 16; ++q) {
        float4 c = wc[q];
        preg[q * 4 + 0] += e * c.x; preg[q * 4 + 1] += e * c.y;
        preg[q * 4 + 2] += e * c.z; preg[q * 4 + 3] += e * c.w;
      }
    }
  }
  BAR();

  // ---- overwrite s_buf with encW (stride 128); also stage s_wc / s_qp ----
  for (int idx = tid; idx < N_ * 32; idx += 256) {
    int row = idx >> 5, q = idx & 31;
    float4 v = *(const float4*)(encW + ((long long)b * N_ + row) * H_ + q * 4);
    float* d = s_buf + row * 128 + q * 4;
    d[0] = v.x; d[1] = v.y; d[2] = v.z; d[3] = v.w;
  }
  if (tid < 128) { s_wc[tid] = wcr; s_qp[tid] = qp0; }
  BAR();

  // ---- initial mask + peeled A_0 (amax=0, cap=initial) ----
  unsigned long long m1lo = 1ull, m1hi = 0ull;
  unsigned long long msklo, mskhi;
  {
    bool p0i = (lane == 0) || (dem0 > cap);
    bool p1i = (lane < 37) ? (dem1 > cap) : true;
    msklo = __ballot(p0i);
    mskhi = __ballot(p1i) & M37;
    if (msklo == ~0ull && mskhi == M37) msklo &= ~1ull;
  }
  float logpAcc = 0.f;
  compat_softmax(wave, lane, 0, cap, msklo, mskhi, s_buf, s_wc, s_qp, s_qs, kreg, s_sc);
  BAR();

  for (int t = 0; t < T_; ++t) {
    int tn = (t + 1 < T_) ? (t + 1) : t;
    float qn = (tid < 128) ? Qpool[((long long)tn * B_ + b) * H_ + tid] : 0.f;

    // ---- B: glimpse partial (role B) ----
    {
      int h = bj >> 4;
      const float* srow = s_sc + h * 104;
      float acc = 0.f;
      if (bh == 0) {
#pragma unroll
        for (int q = 0; q < 12; ++q) {
          float4 sv = *(const float4*)(srow + q * 4);
          acc += sv.x * vreg[q * 4 + 0] + sv.y * vreg[q * 4 + 1]
               + sv.z * vreg[q * 4 + 2] + sv.w * vreg[q * 4 + 3];
        }
        acc += srow[48] * vreg[48] + srow[49] * vreg[49] + srow[50] * vreg[50];
      } else {
        acc += srow[51] * vreg[0];
#pragma unroll
        for (int q = 0; q < 12; ++q) {
          float4 sv = *(const float4*)(srow + 52 + q * 4);
          acc += sv.x * vreg[1 + q * 4] + sv.y * vreg[2 + q * 4]
               + sv.z * vreg[3 + q * 4] + sv.w * vreg[4 + q * 4];
        }
        acc += srow[100] * vreg[49];
      }
      s_part[bh * 128 + bj] = acc;
    }
    BAR();

    // ---- C: comp2 partial (role A) + s_qp refresh ----
    if (an < N_) {
      const float4* p0 = (const float4*)(s_part + aj * 64);
      const float4* p1 = (const float4*)(s_part + 128 + aj * 64);
      float c = 0.f;
#pragma unroll
      for (int q = 0; q < 16; ++q) {
        float4 g0 = p0[q], g1 = p1[q];
        float gx = g0.x + g1.x, gy = g0.y + g1.y, gz = g0.z + g1.z, gw = g0.w + g1.w;
        c += gx * preg[q * 4 + 0] + gy * preg[q * 4 + 1]
           + gz * preg[q * 4 + 2] + gw * preg[q * 4 + 3];
      }
      s_p2[aj * 128 + an] = c;
    }
    if (tid < 128) s_qp[tid] = qn;
    BAR();

    // ---- DA: logits, argmax, lse, state, then fused next-step compat ----
    {
      float l0 = -INFINITY, l1 = -INFINITY;
      bool mb0 = (msklo >> lane) & 1ull;
      if (!mb0) l0 = 10.f * tanhf((s_p2[lane] + s_p2[128 + lane]) * invSqrtH);
      if (lane < 37) {
        bool mb1 = (mskhi >> lane) & 1ull;
        if (!mb1) l1 = 10.f * tanhf((s_p2[64 + lane] + s_p2[192 + lane]) * invSqrtH);
      }
      float vmax = wave_max64(fmaxf(l0, l1));
      unsigned long long blo = __ballot(l0 == vmax);
      unsigned long long bhi = __ballot(l1 == vmax);
      int amax = blo ? (__ffsll((long long)blo) - 1)
                     : (64 + __ffsll((long long)bhi) - 1);
      float ss = wave_sum64(__expf(l0 - vmax) + __expf(l1 - vmax));  // logp path only
      logpAcc -= __logf(ss);

      float dlo = __int_as_float(__builtin_amdgcn_readlane(__float_as_int(dem0), amax & 63));
      float dhi = __int_as_float(__builtin_amdgcn_readlane(__float_as_int(dem1), amax & 63));
      float capNew = (amax == 0) ? cap0 : (cap - ((amax < 64) ? dlo : dhi));
      if (amax < 64) m1lo |= (1ull << amax); else m1hi |= (1ull << (amax - 64));
      m1lo = (m1lo & ~1ull) | (unsigned long long)(amax == 0);
      bool doneNew = ((int)__popcll(m1lo & ~1ull) + (int)__popcll(m1hi)) >= (N_ - 1);
      bool p0m = ((m1lo >> lane) & 1ull) || (dem0 > capNew);
      bool p1m = (lane < 37) ? (((m1hi >> lane) & 1ull) || (dem1 > capNew)) : true;
      unsigned long long klo = __ballot(p0m);
      unsigned long long khi = __ballot(p1m) & M37;
      if (klo == ~0ull && khi == M37) klo &= ~1ull;
      msklo = klo; mskhi = khi; cap = capNew;

      if (tid == 0) out[(long long)b * T_ + t] = (float)amax;
      if (doneNew) {
        // post-done trajectory is provably all-zeros with zero logp deltas
        for (int tt = t + 1 + tid; tt < T_; tt += 256)
          out[(long long)b * T_ + tt] = 0.f;
        break;
      }
      if (t + 1 < T_)
        compat_softmax(wave, lane, amax, capNew, msklo, mskhi,
                       s_buf, s_wc, s_qp, s_qs, kreg, s_sc);
    }
    BAR();
  }

  if (tid == 0) out[(long long)B_ * T_ + b] = logpAcc;
}

// =====================================================================
extern "C" void kernel_launch(void* const* d_in, const int* in_sizes, int n_in,
                              void* d_out, int out_size, void* d_ws, size_t ws_size,
                              hipStream_t stream)
{
  const float* enc   = (const float*)d_in[0];
  const float* pool  = (const float*)d_in[1];
  const float* cap   = (const float*)d_in[3];
  const float* dem   = (const float*)d_in[4];
  const float* W_fc  = (const float*)d_in[7];   // 129x128
  const float* W_fc1 = (const float*)d_in[8];   // 128x128 (= F)
  const float* W_w   = (const float*)d_in[9];
  const float* W_kk  = (const float*)d_in[10];
  const float* W_vv  = (const float*)d_in[11];
  const float* W_at  = (const float*)d_in[12];
  const float* W_pk  = (const float*)d_in[13];
  float* out = (float*)d_out;
  float* ws  = (float*)d_ws;

  float* Mbuf  = ws;                               // 141 * 16384 (slots 2..140 used)
  float* Abuf  = Mbuf + 141 * 16384;               // 140 * 16384
  float* Qpl   = Abuf + 140 * 16384;               // 140 * 512 * 128
  float* encW  = Qpl + 140 * 512 * 128;            // 512 * 101 * 128
  float* Wfw   = encW + 512 * 101 * 128;           // 16384
  float* Wc    = Wfw + 16384;                      // 16384
  float* wcapb = Wc + 16384;                       // 128

  stage_a<<<13, 256, 0, stream>>>(W_fc, W_w, W_pk, W_at, W_fc1, Wfw, Wc, wcapb, Mbuf);
  stage_b<<<1624, 256, 0, stream>>>(W_fc1, enc, Wfw, Mbuf, encW);
  chainL<<<16, 256, 0, stream>>>(W_fc1, Mbuf, 4);
  chainL<<<32, 256, 0, stream>>>(W_fc1, Mbuf, 8);
  chainL<<<64, 256, 0, stream>>>(W_fc1, Mbuf, 16);
  chainL<<<128, 256, 0, stream>>>(W_fc1, Mbuf, 32);
  chainL<<<256, 256, 0, stream>>>(W_fc1, Mbuf, 64);
  stage_n8<<<556, 256, 0, stream>>>(W_fc1, W_w, Mbuf, Abuf);
  stage_n9<<<2084, 256, 0, stream>>>(W_w, pool, Mbuf, Abuf, Qpl);
  stage_n10<<<208, 256, 0, stream>>>(pool, Abuf, Qpl);
  decode_kernel<<<512, 256, 0, stream>>>(enc, W_kk, W_vv, Wc, encW, Qpl, wcapb, cap, dem, out);
}